// Round 1
// baseline (631.712 us; speedup 1.0000x reference)
//
#include <hip/hip_runtime.h>
#include <hip/hip_bf16.h>
#include <stdint.h>

#define GN 8192
#define ALPHA 0.2f

typedef float f32x4 __attribute__((ext_vector_type(4)));
typedef short s16x8 __attribute__((ext_vector_type(8)));

__device__ __forceinline__ unsigned short f2bf(float f) {
    unsigned int u = __float_as_uint(f);
    u += 0x7FFFu + ((u >> 16) & 1u);
    return (unsigned short)(u >> 16);
}
__device__ __forceinline__ float bf2f(unsigned short h) {
    return __uint_as_float(((unsigned int)h) << 16);
}

// w1[k] = sum_o W[k][o]*a[o];  w2[k] = sum_o W[k][o]*a[256+o]
__global__ void kA(const float* __restrict__ W, const float* __restrict__ a,
                   float* __restrict__ w1, float* __restrict__ w2) {
    int k = threadIdx.x;
    const float* row = W + k * 256;
    float s1 = 0.f, s2 = 0.f;
    for (int o = 0; o < 256; ++o) {
        float w = row[o];
        s1 += w * a[o];
        s2 += w * a[256 + o];
    }
    w1[k] = s1;
    w2[k] = s2;
}

// wtT[o][k] = bf16(wtrans[k][o]),  o<256, k<512
__global__ void kA2(const float* __restrict__ wt, unsigned short* __restrict__ wtT) {
    int k = blockIdx.x;
    int o = threadIdx.x;
    wtT[(size_t)o * 512 + k] = f2bf(wt[(size_t)k * 256 + o]);
}

// s = inp@w1, t = inp@w2, inpT[c][r] = bf16(inp[r][c])
__global__ __launch_bounds__(256) void kB(const float* __restrict__ inp,
                                          const float* __restrict__ w1,
                                          const float* __restrict__ w2,
                                          float* __restrict__ s, float* __restrict__ t,
                                          unsigned short* __restrict__ inpT) {
    __shared__ unsigned short T[256][33];
    const int tid = threadIdx.x;
    const int r0 = blockIdx.x * 32;
    const int r = tid >> 3, cs = tid & 7;
    const float4* in4 = (const float4*)(inp + (size_t)(r0 + r) * 256 + cs * 32);
    const float4* w14 = (const float4*)(w1 + cs * 32);
    const float4* w24 = (const float4*)(w2 + cs * 32);
    float zs = 0.f, zt = 0.f;
#pragma unroll
    for (int q = 0; q < 8; ++q) {
        float4 v = in4[q];
        float4 a1 = w14[q];
        float4 a2 = w24[q];
        zs += v.x * a1.x + v.y * a1.y + v.z * a1.z + v.w * a1.w;
        zt += v.x * a2.x + v.y * a2.y + v.z * a2.z + v.w * a2.w;
        int c = cs * 32 + q * 4;
        T[c + 0][r] = f2bf(v.x);
        T[c + 1][r] = f2bf(v.y);
        T[c + 2][r] = f2bf(v.z);
        T[c + 3][r] = f2bf(v.w);
    }
#pragma unroll
    for (int off = 1; off < 8; off <<= 1) {
        zs += __shfl_xor(zs, off);
        zt += __shfl_xor(zt, off);
    }
    if (cs == 0) {
        s[r0 + r] = zs;
        t[r0 + r] = zt;
    }
    __syncthreads();
    unsigned short* dst = inpT + (size_t)tid * GN + r0;
    ushort4* d4 = (ushort4*)dst;
#pragma unroll
    for (int q = 0; q < 8; ++q) {
        ushort4 v;
        v.x = T[tid][q * 4 + 0];
        v.y = T[tid][q * 4 + 1];
        v.z = T[tid][q * 4 + 2];
        v.w = T[tid][q * 4 + 3];
        d4[q] = v;
    }
}

// Fused masked double-softmax attention: per 16-row block, stream adj,
// p+ = adj?exp(lrelu(s+t)):0, p- = adj?exp(-lrelu(s+t)):0 (bf16),
// accumulate num± = P± @ inp (MFMA), Z± = row-sums; store hd = [num+/Z+, -num-/Z-] bf16.
__global__ __launch_bounds__(256) void kC(const int* __restrict__ adj,
                                          const float* __restrict__ s,
                                          const float* __restrict__ t,
                                          const unsigned short* __restrict__ inpT,
                                          unsigned short* __restrict__ hd) {
    __shared__ unsigned short ptP[1024];  // 16 x 64 bf16, XOR-swizzled
    __shared__ unsigned short ptN[1024];
    __shared__ float Zp[16], Zn[16];
    const int tid = threadIdx.x;
    const int lane = tid & 63, w = tid >> 6;
    const int r = tid >> 4, c4 = tid & 15;  // p-compute role: row r, col-chunk c4*4
    const int i0 = blockIdx.x * 16;
    const float sr = s[i0 + r];
    float zp = 0.f, zn = 0.f;
    f32x4 accP[4], accN[4];
#pragma unroll
    for (int n = 0; n < 4; ++n) {
        accP[n] = (f32x4)(0.f);
        accN[n] = (f32x4)(0.f);
    }
    const int fbase = w * 64;
    const int rr = lane & 15, hi = lane >> 4;  // MFMA fragment role
    const int wbyte = (r * 128 + c4 * 8) ^ ((r & 7) << 4);
    char* wP = (char*)ptP + wbyte;
    char* wN = (char*)ptN + wbyte;
    const size_t adjbase = (size_t)(i0 + r) * GN + c4 * 4;

    for (int jb = 0; jb < GN / 64; ++jb) {
        int4 av = *(const int4*)(adj + adjbase + jb * 64);
        float4 tv = *(const float4*)(t + jb * 64 + c4 * 4);
        float ev[4] = {tv.x, tv.y, tv.z, tv.w};
        int am[4] = {av.x, av.y, av.z, av.w};
        unsigned short ub[8];
#pragma unroll
        for (int q = 0; q < 4; ++q) {
            float e = sr + ev[q];
            float l = e > 0.f ? e : ALPHA * e;
            float p1 = am[q] ? __expf(l) : 0.f;
            float p2 = am[q] ? __expf(-l) : 0.f;
            unsigned short b1 = f2bf(p1), b2 = f2bf(p2);
            zp += bf2f(b1);
            zn += bf2f(b2);
            ub[q] = b1;
            ub[4 + q] = b2;
        }
        __syncthreads();  // previous iter's MFMA reads done before overwrite
        *(ushort4*)wP = make_ushort4(ub[0], ub[1], ub[2], ub[3]);
        *(ushort4*)wN = make_ushort4(ub[4], ub[5], ub[6], ub[7]);
        __syncthreads();  // p tiles visible
#pragma unroll
        for (int kc = 0; kc < 2; ++kc) {
            const int rbyte = (rr * 128 + kc * 64 + hi * 16) ^ ((rr & 7) << 4);
            s16x8 aP = *(const s16x8*)((char*)ptP + rbyte);
            s16x8 aN = *(const s16x8*)((char*)ptN + rbyte);
#pragma unroll
            for (int nt = 0; nt < 4; ++nt) {
                const unsigned short* bp =
                    inpT + (size_t)(fbase + nt * 16 + rr) * GN + jb * 64 + kc * 32 + hi * 8;
                s16x8 bv = *(const s16x8*)bp;
                accP[nt] = __builtin_amdgcn_mfma_f32_16x16x32_bf16(aP, bv, accP[nt], 0, 0, 0);
                accN[nt] = __builtin_amdgcn_mfma_f32_16x16x32_bf16(aN, bv, accN[nt], 0, 0, 0);
            }
        }
    }
    // Z row-reduction across the 16 lanes sharing row r
#pragma unroll
    for (int off = 1; off < 16; off <<= 1) {
        zp += __shfl_xor(zp, off);
        zn += __shfl_xor(zn, off);
    }
    if (c4 == 0) {
        Zp[r] = zp;
        Zn[r] = zn;
    }
    __syncthreads();
#pragma unroll
    for (int nt = 0; nt < 4; ++nt) {
        int col = fbase + nt * 16 + rr;
#pragma unroll
        for (int reg = 0; reg < 4; ++reg) {
            int row = hi * 4 + reg;  // C layout: col=lane&15, row=(lane>>4)*4+reg
            float vp = accP[nt][reg] / Zp[row];
            float vn = -accN[nt][reg] / Zn[row];
            hd[(size_t)(i0 + row) * 512 + col] = f2bf(vp);
            hd[(size_t)(i0 + row) * 512 + 256 + col] = f2bf(vn);
        }
    }
}

// out = elu(hd @ wtrans):  M=8192, K=512, N=256
__global__ __launch_bounds__(256) void kD(const unsigned short* __restrict__ hd,
                                          const unsigned short* __restrict__ wtT,
                                          float* __restrict__ out) {
    const int tid = threadIdx.x;
    const int lane = tid & 63, w = tid >> 6;
    const int rr = lane & 15, hi = lane >> 4;
    const int i0 = blockIdx.x * 32;
    f32x4 acc[2][4];
#pragma unroll
    for (int m = 0; m < 2; ++m)
#pragma unroll
        for (int n = 0; n < 4; ++n) acc[m][n] = (f32x4)(0.f);
#pragma unroll 4
    for (int kc = 0; kc < 16; ++kc) {
        s16x8 a[2];
#pragma unroll
        for (int m = 0; m < 2; ++m)
            a[m] = *(const s16x8*)(hd + (size_t)(i0 + m * 16 + rr) * 512 + kc * 32 + hi * 8);
#pragma unroll
        for (int n = 0; n < 4; ++n) {
            s16x8 b = *(const s16x8*)(wtT + (size_t)(w * 64 + n * 16 + rr) * 512 + kc * 32 + hi * 8);
            acc[0][n] = __builtin_amdgcn_mfma_f32_16x16x32_bf16(a[0], b, acc[0][n], 0, 0, 0);
            acc[1][n] = __builtin_amdgcn_mfma_f32_16x16x32_bf16(a[1], b, acc[1][n], 0, 0, 0);
        }
    }
#pragma unroll
    for (int m = 0; m < 2; ++m)
#pragma unroll
        for (int n = 0; n < 4; ++n) {
            int col = w * 64 + n * 16 + rr;
#pragma unroll
            for (int reg = 0; reg < 4; ++reg) {
                int row = i0 + m * 16 + hi * 4 + reg;
                float x = acc[m][n][reg];
                out[(size_t)row * 256 + col] = x > 0.f ? x : __expf(x) - 1.f;
            }
        }
}

extern "C" void kernel_launch(void* const* d_in, const int* in_sizes, int n_in,
                              void* d_out, int out_size, void* d_ws, size_t ws_size,
                              hipStream_t stream) {
    const float* inp = (const float*)d_in[0];
    const int* adj = (const int*)d_in[1];
    const float* W = (const float*)d_in[2];
    const float* a = (const float*)d_in[3];
    const float* wt = (const float*)d_in[4];
    float* out = (float*)d_out;
    char* ws = (char*)d_ws;

    unsigned short* inpT = (unsigned short*)ws;                   // 4 MB  [256][8192] bf16
    unsigned short* hd = (unsigned short*)(ws + (4 << 20));       // 8 MB  [8192][512] bf16
    float* s = (float*)(ws + (12 << 20));                         // 32 KB
    float* t = (float*)(ws + (12 << 20) + 32 * 1024);             // 32 KB
    float* w1 = (float*)(ws + (12 << 20) + 64 * 1024);            // 1 KB
    float* w2 = (float*)(ws + (12 << 20) + 68 * 1024);            // 1 KB
    unsigned short* wtT = (unsigned short*)(ws + (12 << 20) + 72 * 1024);  // 256 KB

    hipLaunchKernelGGL(kA, dim3(1), dim3(256), 0, stream, W, a, w1, w2);
    hipLaunchKernelGGL(kA2, dim3(512), dim3(256), 0, stream, wt, wtT);
    hipLaunchKernelGGL(kB, dim3(256), dim3(256), 0, stream, inp, w1, w2, s, t, inpT);
    hipLaunchKernelGGL(kC, dim3(GN / 16), dim3(256), 0, stream, adj, s, t, inpT, hd);
    hipLaunchKernelGGL(kD, dim3(GN / 32), dim3(256), 0, stream, hd, wtT, out);
}

// Round 3
// 474.346 us; speedup vs baseline: 1.3318x; 1.3318x over previous
//
#include <hip/hip_runtime.h>
#include <stdint.h>

#define GN 8192

typedef float f32x4 __attribute__((ext_vector_type(4)));
typedef short s16x8 __attribute__((ext_vector_type(8)));
typedef unsigned short u16x8 __attribute__((ext_vector_type(8)));

__device__ __forceinline__ unsigned short f2bf(float f) {
    unsigned int u = __float_as_uint(f);
    u += 0x7FFFu + ((u >> 16) & 1u);
    return (unsigned short)(u >> 16);
}
__device__ __forceinline__ float bf2f(unsigned short h) {
    return __uint_as_float(((unsigned int)h) << 16);
}

// w1[k] = sum_o W[k][o]*a[o];  w2[k] = sum_o W[k][o]*a[256+o]. One wave per k.
__global__ void kA(const float* __restrict__ W, const float* __restrict__ a,
                   float* __restrict__ w1, float* __restrict__ w2) {
    int k = blockIdx.x, l = threadIdx.x;
    float s1 = 0.f, s2 = 0.f;
#pragma unroll
    for (int q = 0; q < 4; ++q) {
        int o = l + q * 64;
        float w = W[k * 256 + o];
        s1 += w * a[o];
        s2 += w * a[256 + o];
    }
#pragma unroll
    for (int off = 32; off; off >>= 1) {
        s1 += __shfl_xor(s1, off);
        s2 += __shfl_xor(s2, off);
    }
    if (l == 0) {
        w1[k] = s1;
        w2[k] = s2;
    }
}

// wtT[o][k] = bf16(wtrans[k][o]),  o<256, k<512
__global__ void kA2(const float* __restrict__ wt, unsigned short* __restrict__ wtT) {
    int k = blockIdx.x;
    int o = threadIdx.x;
    wtT[(size_t)o * 512 + k] = f2bf(wt[(size_t)k * 256 + o]);
}

// s = inp@w1, t = inp@w2, inpT[c][r] = bf16(inp[r][c])
__global__ __launch_bounds__(256) void kB(const float* __restrict__ inp,
                                          const float* __restrict__ w1,
                                          const float* __restrict__ w2,
                                          float* __restrict__ s, float* __restrict__ t,
                                          unsigned short* __restrict__ inpT) {
    __shared__ unsigned short T[256][33];
    const int tid = threadIdx.x;
    const int r0 = blockIdx.x * 32;
    const int r = tid >> 3, cs = tid & 7;
    const float4* in4 = (const float4*)(inp + (size_t)(r0 + r) * 256 + cs * 32);
    const float4* w14 = (const float4*)(w1 + cs * 32);
    const float4* w24 = (const float4*)(w2 + cs * 32);
    float zs = 0.f, zt = 0.f;
#pragma unroll
    for (int q = 0; q < 8; ++q) {
        float4 v = in4[q];
        float4 a1 = w14[q];
        float4 a2 = w24[q];
        zs += v.x * a1.x + v.y * a1.y + v.z * a1.z + v.w * a1.w;
        zt += v.x * a2.x + v.y * a2.y + v.z * a2.z + v.w * a2.w;
        int c = cs * 32 + q * 4;
        T[c + 0][r] = f2bf(v.x);
        T[c + 1][r] = f2bf(v.y);
        T[c + 2][r] = f2bf(v.z);
        T[c + 3][r] = f2bf(v.w);
    }
#pragma unroll
    for (int off = 1; off < 8; off <<= 1) {
        zs += __shfl_xor(zs, off);
        zt += __shfl_xor(zt, off);
    }
    if (cs == 0) {
        s[r0 + r] = zs;
        t[r0 + r] = zt;
    }
    __syncthreads();
    unsigned short* dst = inpT + (size_t)tid * GN + r0;
    ushort4* d4 = (ushort4*)dst;
#pragma unroll
    for (int q = 0; q < 8; ++q) {
        ushort4 v;
        v.x = T[tid][q * 4 + 0];
        v.y = T[tid][q * 4 + 1];
        v.z = T[tid][q * 4 + 2];
        v.w = T[tid][q * 4 + 3];
        d4[q] = v;
    }
}

#define PROC(AM, TX, BP, BN)                  \
    {                                         \
        float e = sr + (TX);                  \
        float l = fmaxf(e, 0.2f * e);         \
        float p1 = (AM) ? __expf(l) : 0.f;    \
        float p2 = (AM) ? __expf(-l) : 0.f;   \
        unsigned short b1 = f2bf(p1);         \
        unsigned short b2 = f2bf(p2);         \
        zp += bf2f(b1);                       \
        zn += bf2f(b2);                       \
        BP = b1;                              \
        BN = b2;                              \
    }

// Fully fused: masked double-softmax attention + output GEMM + elu.
// Block: 32 rows x all 8192 cols, 512 threads / 8 waves, grid 256.
__global__ __launch_bounds__(512, 2) void kC(const int* __restrict__ adj,
                                             const float* __restrict__ sv,
                                             const float* __restrict__ tv,
                                             const unsigned short* __restrict__ inpT,
                                             const unsigned short* __restrict__ wtT,
                                             float* __restrict__ out) {
    __shared__ unsigned short ptP[32 * 256];  // [32][256] bf16, XOR-swizzled (16 KB)
    __shared__ unsigned short ptN[32 * 256];  // 16 KB
    __shared__ unsigned short hdl[32 * 512];  // [32][512] bf16, XOR-swizzled (32 KB)
    __shared__ float Zs[64];
    const int tid = threadIdx.x;
    const int lane = tid & 63, w = tid >> 6;
    const int rr = lane & 15, hi = lane >> 4;
    const int r = tid >> 4, c4 = tid & 15;  // p-compute role: row r, col chunk c4*16
    const int i0 = blockIdx.x * 32;
    const float sr = sv[i0 + r];
    float zp = 0.f, zn = 0.f;
    f32x4 accP[2][2], accN[2][2];
#pragma unroll
    for (int m = 0; m < 2; ++m)
#pragma unroll
        for (int n = 0; n < 2; ++n) {
            accP[m][n] = (f32x4)(0.f);
            accN[m][n] = (f32x4)(0.f);
        }
    const int fb = w * 32;  // this wave's 32-feature slice
    char* ldsP = (char*)ptP;
    char* ldsN = (char*)ptN;
    const int swz = (r & 7) << 4;
    const int wb0 = (r * 512 + c4 * 32) ^ swz;
    const int wb1 = (r * 512 + c4 * 32 + 16) ^ swz;
    const size_t arow = (size_t)(i0 + r) * GN + c4 * 16;
    const float* tb = tv + c4 * 16;

    // prologue: prefetch chunk 0 adjacency + t
    int4 ca0 = *(const int4*)(adj + arow);
    int4 ca1 = *(const int4*)(adj + arow + 4);
    int4 ca2 = *(const int4*)(adj + arow + 8);
    int4 ca3 = *(const int4*)(adj + arow + 12);
    float4 tf0 = *(const float4*)(tb);
    float4 tf1 = *(const float4*)(tb + 4);
    float4 tf2 = *(const float4*)(tb + 8);
    float4 tf3 = *(const float4*)(tb + 12);

    for (int jc = 0; jc < 32; ++jc) {
        // issue this chunk's B loads first (L2-resident inpT) -> registers
        s16x8 bvr[16];
        const unsigned short* bcol = inpT + jc * 256 + hi * 8;
#pragma unroll
        for (int kc = 0; kc < 8; ++kc) {
            bvr[kc * 2 + 0] = *(const s16x8*)(bcol + (size_t)(fb + rr) * GN + kc * 32);
            bvr[kc * 2 + 1] = *(const s16x8*)(bcol + (size_t)(fb + 16 + rr) * GN + kc * 32);
        }
        // exp phase on prefetched adj/t (overlaps with B loads in flight)
        u16x8 up0, up1, un0, un1;
        PROC(ca0.x, tf0.x, up0[0], un0[0]);
        PROC(ca0.y, tf0.y, up0[1], un0[1]);
        PROC(ca0.z, tf0.z, up0[2], un0[2]);
        PROC(ca0.w, tf0.w, up0[3], un0[3]);
        PROC(ca1.x, tf1.x, up0[4], un0[4]);
        PROC(ca1.y, tf1.y, up0[5], un0[5]);
        PROC(ca1.z, tf1.z, up0[6], un0[6]);
        PROC(ca1.w, tf1.w, up0[7], un0[7]);
        PROC(ca2.x, tf2.x, up1[0], un1[0]);
        PROC(ca2.y, tf2.y, up1[1], un1[1]);
        PROC(ca2.z, tf2.z, up1[2], un1[2]);
        PROC(ca2.w, tf2.w, up1[3], un1[3]);
        PROC(ca3.x, tf3.x, up1[4], un1[4]);
        PROC(ca3.y, tf3.y, up1[5], un1[5]);
        PROC(ca3.z, tf3.z, up1[6], un1[6]);
        PROC(ca3.w, tf3.w, up1[7], un1[7]);
        // prefetch next chunk's adj + t (stay in flight across the raw barriers)
        if (jc < 31) {
            const int* an = adj + arow + (jc + 1) * 256;
            ca0 = *(const int4*)(an);
            ca1 = *(const int4*)(an + 4);
            ca2 = *(const int4*)(an + 8);
            ca3 = *(const int4*)(an + 12);
            const float* tn = tb + (jc + 1) * 256;
            tf0 = *(const float4*)(tn);
            tf1 = *(const float4*)(tn + 4);
            tf2 = *(const float4*)(tn + 8);
            tf3 = *(const float4*)(tn + 12);
        }
        // barrier 1: previous MFMA phase's LDS reads complete before overwrite
        asm volatile("" ::: "memory");
        __builtin_amdgcn_s_barrier();
        asm volatile("" ::: "memory");
        *(u16x8*)(ldsP + wb0) = up0;
        *(u16x8*)(ldsP + wb1) = up1;
        *(u16x8*)(ldsN + wb0) = un0;
        *(u16x8*)(ldsN + wb1) = un1;
        // barrier 2: LDS writes visible; do NOT drain vmcnt (prefetches in flight)
        asm volatile("s_waitcnt lgkmcnt(0)" ::: "memory");
        __builtin_amdgcn_s_barrier();
        asm volatile("" ::: "memory");
        // MFMA phase: pure LDS reads + register B
#pragma unroll
        for (int kc = 0; kc < 8; ++kc) {
            int rb0 = (rr * 512 + kc * 64 + hi * 16) ^ ((rr & 7) << 4);
            s16x8 aP0 = *(const s16x8*)(ldsP + rb0);
            s16x8 aP1 = *(const s16x8*)(ldsP + rb0 + 8192);  // rows 16..31: (16+rr)&7==rr&7
            s16x8 aN0 = *(const s16x8*)(ldsN + rb0);
            s16x8 aN1 = *(const s16x8*)(ldsN + rb0 + 8192);
            accP[0][0] = __builtin_amdgcn_mfma_f32_16x16x32_bf16(aP0, bvr[kc * 2 + 0], accP[0][0], 0, 0, 0);
            accP[1][0] = __builtin_amdgcn_mfma_f32_16x16x32_bf16(aP1, bvr[kc * 2 + 0], accP[1][0], 0, 0, 0);
            accN[0][0] = __builtin_amdgcn_mfma_f32_16x16x32_bf16(aN0, bvr[kc * 2 + 0], accN[0][0], 0, 0, 0);
            accN[1][0] = __builtin_amdgcn_mfma_f32_16x16x32_bf16(aN1, bvr[kc * 2 + 0], accN[1][0], 0, 0, 0);
            accP[0][1] = __builtin_amdgcn_mfma_f32_16x16x32_bf16(aP0, bvr[kc * 2 + 1], accP[0][1], 0, 0, 0);
            accP[1][1] = __builtin_amdgcn_mfma_f32_16x16x32_bf16(aP1, bvr[kc * 2 + 1], accP[1][1], 0, 0, 0);
            accN[0][1] = __builtin_amdgcn_mfma_f32_16x16x32_bf16(aN0, bvr[kc * 2 + 1], accN[0][1], 0, 0, 0);
            accN[1][1] = __builtin_amdgcn_mfma_f32_16x16x32_bf16(aN1, bvr[kc * 2 + 1], accN[1][1], 0, 0, 0);
        }
    }
    // Z reduce across the 16 lanes sharing row r
#pragma unroll
    for (int off = 1; off < 16; off <<= 1) {
        zp += __shfl_xor(zp, off);
        zn += __shfl_xor(zn, off);
    }
    if (c4 == 0) {
        Zs[r] = zp;
        Zs[32 + r] = zn;
    }
    __syncthreads();
    // hd tile -> LDS (bf16, swizzled): hd = [num+/Z+, -num-/Z-]
#pragma unroll
    for (int m = 0; m < 2; ++m)
#pragma unroll
        for (int reg = 0; reg < 4; ++reg) {
            int row = m * 16 + hi * 4 + reg;
            float izp = 1.f / Zs[row];
            float izn = 1.f / Zs[32 + row];
            int sw = (row & 7) << 4;
#pragma unroll
            for (int nt = 0; nt < 2; ++nt) {
                int col = fb + nt * 16 + rr;
                *(unsigned short*)((char*)hdl + ((row * 1024 + col * 2) ^ sw)) =
                    f2bf(accP[m][nt][reg] * izp);
                *(unsigned short*)((char*)hdl + ((row * 1024 + (col + 256) * 2) ^ sw)) =
                    f2bf(-accN[m][nt][reg] * izn);
            }
        }
    __syncthreads();
    // output GEMM: out[32][256] = elu(hdl[32][512] @ wtT^T), wave w does cols w*32..+31
    f32x4 oc[2][2];
#pragma unroll
    for (int m = 0; m < 2; ++m)
#pragma unroll
        for (int nt = 0; nt < 2; ++nt) oc[m][nt] = (f32x4)(0.f);
    const int n0 = w * 32;
#pragma unroll
    for (int kc = 0; kc < 16; ++kc) {
        int rbs = (rr & 7) << 4;
        s16x8 a0 = *(const s16x8*)((char*)hdl + ((rr * 1024 + kc * 64 + hi * 16) ^ rbs));
        s16x8 a1 = *(const s16x8*)((char*)hdl + (((16 + rr) * 1024 + kc * 64 + hi * 16) ^ rbs));
#pragma unroll
        for (int nt = 0; nt < 2; ++nt) {
            s16x8 b = *(const s16x8*)(wtT + (size_t)(n0 + nt * 16 + rr) * 512 + kc * 32 + hi * 8);
            oc[0][nt] = __builtin_amdgcn_mfma_f32_16x16x32_bf16(a0, b, oc[0][nt], 0, 0, 0);
            oc[1][nt] = __builtin_amdgcn_mfma_f32_16x16x32_bf16(a1, b, oc[1][nt], 0, 0, 0);
        }
    }
#pragma unroll
    for (int m = 0; m < 2; ++m)
#pragma unroll
        for (int nt = 0; nt < 2; ++nt) {
            int col = n0 + nt * 16 + rr;
#pragma unroll
            for (int reg = 0; reg < 4; ++reg) {
                int row = i0 + m * 16 + hi * 4 + reg;
                float x = oc[m][nt][reg];
                out[(size_t)row * 256 + col] = x > 0.f ? x : __expf(x) - 1.f;
            }
        }
}

extern "C" void kernel_launch(void* const* d_in, const int* in_sizes, int n_in,
                              void* d_out, int out_size, void* d_ws, size_t ws_size,
                              hipStream_t stream) {
    const float* inp = (const float*)d_in[0];
    const int* adj = (const int*)d_in[1];
    const float* W = (const float*)d_in[2];
    const float* a = (const float*)d_in[3];
    const float* wt = (const float*)d_in[4];
    float* out = (float*)d_out;
    char* ws = (char*)d_ws;

    unsigned short* inpT = (unsigned short*)ws;                 // 4 MB  [256][8192] bf16
    float* s = (float*)(ws + (4 << 20));                        // 32 KB
    float* t = (float*)(ws + (4 << 20) + (1 << 15));            // 32 KB
    float* w1 = (float*)(ws + (4 << 20) + (2 << 15));           // 1 KB
    float* w2 = (float*)(ws + (4 << 20) + (2 << 15) + 4096);    // 1 KB
    unsigned short* wtT = (unsigned short*)(ws + (4 << 20) + (2 << 15) + 8192);  // 256 KB

    hipLaunchKernelGGL(kA, dim3(256), dim3(64), 0, stream, W, a, w1, w2);
    hipLaunchKernelGGL(kA2, dim3(512), dim3(256), 0, stream, wt, wtT);
    hipLaunchKernelGGL(kB, dim3(256), dim3(256), 0, stream, inp, w1, w2, s, t, inpT);
    hipLaunchKernelGGL(kC, dim3(256), dim3(512), 0, stream, adj, s, t, inpT, wtT, out);
}